// Round 4
// baseline (1230.635 us; speedup 1.0000x reference)
//
#include <hip/hip_runtime.h>
#include <hip/hip_bf16.h>

// BlurredNoise via MFMA implicit GEMM, round 12 = 32x32x16 MFMA rewrite.
// R8==R9 elapsed with equal per-CU LDS demand (and halved/doubled everything
// else) -> LDS pipe is the wall, dominated by A-fragment ds_read_b64 pairs
// (1700/wave). Fix: mfma_f32_32x32x16_bf16 -> ONE 1KB A-read per 16-tap
// k-step serves all live filter tiles: ~313 ds_read_b128/wave (-80% LDS
// instrs). Same proven R8/R9 skeleton: 1-wave blocks, 2048 blocks, no
// barriers, B global->reg rotation, per-wave LDS x staging. x staged as
// EIGHT shifted bf16 copies (c=row&7) so each lane's 16B A fragment is
// 16B-aligned (single b128, bank-uniform). R11 lesson: no cooperative
// staging / no new lambda machinery (scratch blowup).
// out[bc][F][t] = scale[F] * sum_j x[bc][t+j] * k[F][j]

#define KS      5000
#define IN_SEQ  9095
#define T_OUT   4096
#define NBC     16
#define NF      128
#define NSTEP   313               // 16-tap k-steps
#define SWZSTEP 328               // padded per-tile step stride (rows)
#define CSTRIDE 1056              // bytes; /4 = 264 == 8 mod 32 -> uniform banks
#define XBUF    (8*CSTRIDE)       // 8448 B per parity buffer (8 shifted copies)
#define XPS     9344              // padded x row stride (floats), front pad 32
#define XTAIL   256               // zero tail for staging over-reads (unread)
#define SWZ_BYTES (4*SWZSTEP*1024)    // 1,343,488

typedef __attribute__((ext_vector_type(8)))  short v8s;
typedef __attribute__((ext_vector_type(4)))  float v4f;
typedef __attribute__((ext_vector_type(16))) float v16f;

__device__ __forceinline__ unsigned short f2b(float v) {
  union { __hip_bfloat16 h; unsigned short u; } cv;
  cv.h = __float2bfloat16(v);   // RNE
  return cv.u;
}

// ---- fused pre-kernel: (a) filters -> 32x32x16 B-frags; (b) padded x copy ----
__global__ void build_pre(const float* __restrict__ filt,
                          const float* __restrict__ noise,
                          unsigned short* __restrict__ swz,
                          float* __restrict__ xpad) {
  const int b = blockIdx.x;
  if (b < 313) {                       // swz job: 4 tiles x 313 steps, 64 lanes/frag
    const int i = b * 256 + threadIdx.x;
    if (i >= 4 * NSTEP * 64) return;
    const int lane = i & 63;
    const int frag = i >> 6;
    const int ft = frag / NSTEP;
    const int s  = frag - ft * NSTEP;
    const int col = lane & 31;          // filter within tile
    const int hi  = lane >> 5;          // k-group (8 taps)
    const int jg0 = KS - 16 * (s + 1) + 8 * hi;
    const float* row = filt + (size_t)(ft * 32 + col) * KS;
    unsigned short o[8];
    #pragma unroll
    for (int j = 0; j < 8; ++j) {
      int jg = jg0 + j;
      int jc = jg < 0 ? 0 : jg;          // clamp ADDRESS, select VALUE
      float v = (jg >= 0) ? row[jc] : 0.0f;
      o[j] = f2b(v);
    }
    *(uint4*)(swz + (((size_t)(ft * SWZSTEP + s)) << 9) + (lane << 3)) = *(uint4*)o;
  } else {                             // xpad job: 16 x XPS (+tail), zeros outside
    const int i = (b - 313) * 256 + threadIdx.x;
    if (i >= NBC * XPS + XTAIL) return;
    const int r = i / XPS;
    const int pcol = i - r * XPS;
    const int lg = pcol - 32;
    xpad[i] = (r < NBC && lg >= 0 && lg < IN_SEQ) ? noise[r * IN_SEQ + lg] : 0.0f;
  }
}

// ---- one constant-width segment of the k-loop ----
// W: live 32-F tiles (tiles 4-W..3); U: steps/group; NG: groups; SB: first
// step; D: B-prefetch rotation depth (U%D==0 when NG>1). One v8s A-read per
// step feeds all W MFMAs. xb: LDS base (NO restrict - stage_write stores and
// A-reads load through the same provenance, order preserved).
template<int W, int U, int NG, int SB, int D>
__device__ __forceinline__ void run_seg(
    const char* __restrict__ swzg, const float* __restrict__ xn,
    char* xb, int xrd_off, int t0, int lane, v16f (&acc)[4])
{
  v8s breg[D][W];
  v8s areg[2];
  float4 xr[4];
  const char* xrd = xb + xrd_off;      // may-alias xb: ds ordering preserved

  const char* sp[W];
  #pragma unroll
  for (int w = 0; w < W; ++w)
    sp[w] = swzg + (((size_t)((4 - W + w) * SWZSTEP + SB)) << 10) + 16 * lane;

  auto stage_load = [&](int gg) {      // unconditional, aligned (padded buffer)
    const int wb = t0 + KS - 16 * (SB + (gg + 1) * U);
    #pragma unroll
    for (int ii = 0; ii < 4; ++ii)
      xr[ii] = *(const float4*)(xn + (wb + 8 * lane + 4 * ii));
  };
  auto stage_write = [&](int parity) { // xr -> 8 shifted bf16 LDS copies
    const float* f = (const float*)xr;
    unsigned u8v[8];
    #pragma unroll
    for (int j = 0; j < 8; ++j)
      u8v[j] = (unsigned)f2b(f[2 * j]) | ((unsigned)f2b(f[2 * j + 1]) << 16);
    auto AL = [](unsigned hi, unsigned lo) { return (lo >> 16) | (hi << 16); };
    char* buf = xb + parity * XBUF + 16 * lane;
    #pragma unroll
    for (int c = 0; c < 8; ++c) {
      const int h = c >> 1;
      uint4 wv;
      if ((c & 1) == 0)
        wv = (uint4){u8v[h], u8v[h + 1], u8v[h + 2], u8v[h + 3]};
      else
        wv = (uint4){AL(u8v[h + 1], u8v[h]),     AL(u8v[h + 2], u8v[h + 1]),
                     AL(u8v[h + 3], u8v[h + 2]), AL(u8v[h + 4], u8v[h + 3])};
      *(uint4*)(buf + c * CSTRIDE) = wv;
    }
  };

  // prologue: B depth-D, x group0 staged + group1 loaded, A step SB
  #pragma unroll
  for (int d = 0; d < D; ++d)
    #pragma unroll
    for (int w = 0; w < W; ++w)
      breg[d][w] = *(const v8s*)(sp[w] + (d << 10));
  stage_load(0);
  stage_write(0);
  stage_load(NG > 1 ? 1 : 0);
  areg[0] = *(const v8s*)(xrd + 32 * (U - 1));

  #pragma unroll 1
  for (int g = 0; g < NG; ++g) {
    #pragma unroll
    for (int i = 0; i < U; ++i) {
      const int ap = (((U & 1) ? g : 0) + i) & 1;   // step-global A parity
      if (i == 1) stage_write((g + 1) & 1);   // garbage parity-write if g+1==NG (unread)
      if (i == 2) { int gg = g + 2; gg = gg > NG - 1 ? NG - 1 : gg; stage_load(gg); }
      // A prefetch for next step (distance 1, ping-pong)
      {
        const char* pn;
        if (i + 1 < U) {
          pn = xrd + (g & 1) * XBUF + 32 * (U - 2 - i);
        } else {
          int gn = (g + 1 < NG) ? (g + 1) : g;
          pn = xrd + (gn & 1) * XBUF + 32 * (U - 1);
        }
        areg[ap ^ 1] = *(const v8s*)pn;
      }
      // MFMA: one A fragment x W live B tiles
      #pragma unroll
      for (int w = 0; w < W; ++w)
        acc[4 - W + w] = __builtin_amdgcn_mfma_f32_32x32x16_bf16(
            areg[ap], breg[i % D][w], acc[4 - W + w], 0, 0, 0);
      // B refill: slot i%D <- step i+D (pad rows absorb tail over-reads)
      #pragma unroll
      for (int w = 0; w < W; ++w)
        breg[i % D][w] = *(const v8s*)(sp[w] + ((i + D) << 10));
    }
    #pragma unroll
    for (int w = 0; w < W; ++w) sp[w] += (U << 10);
  }
}

// ---- main kernel: 2048 blocks x 64 threads, identical waves, barrier-free ----
__global__ __launch_bounds__(64, 2) void blur_mfma(
    const float* __restrict__ xpad,
    const unsigned short* __restrict__ swz,
    const float* __restrict__ scale,
    float* __restrict__ out)
{
  __shared__ __align__(16) char xb[2 * XBUF];   // 16,896 B
  const int lane = threadIdx.x;
  const int b  = blockIdx.x;
  const int bc = b >> 7;                 // 16 bc x 128 t-chunks
  const int t0 = (b & 127) << 5;         // 32 output t per wave
  const int row = lane & 31, hi = lane >> 5;
  const float* __restrict__ xn = xpad + (size_t)bc * XPS + 32;  // logical origin
  const char* swzg = (const char*)swz;
  // A-read: copy c=row&7, byte 16*(row>>3) + 16*hi (+32*u' per step)
  const int xrd_off = (row & 7) * CSTRIDE + 16 * (row >> 3) + 16 * hi;

  v16f acc[4];
  #pragma unroll
  for (int n = 0; n < 4; ++n)
    #pragma unroll
    for (int j = 0; j < 16; ++j) acc[n][j] = 0.0f;

  // segments: <W, U, NG, SB, D>; live steps: W4 s<20, W3 <49, W2 <124, W1 <313
  run_seg<4, 20, 1,   0, 2>(swzg, xn, xb, xrd_off, t0, lane, acc);
  run_seg<3, 29, 1,  20, 2>(swzg, xn, xb, xrd_off, t0, lane, acc);
  run_seg<2, 25, 3,  49, 5>(swzg, xn, xb, xrd_off, t0, lane, acc);
  run_seg<1, 27, 7, 124, 9>(swzg, xn, xb, xrd_off, t0, lane, acc);

  // epilogue: D col=lane&31 -> F, row=(reg&3)+8*(reg>>2)+4*hi -> t offset
  #pragma unroll
  for (int n = 0; n < 4; ++n) {
    const int F = 32 * n + row;
    const float sc = scale[F];
    float* op = out + (size_t)(bc * NF + F) * T_OUT + t0 + 4 * hi;
    #pragma unroll
    for (int r2 = 0; r2 < 4; ++r2) {
      v4f o = {acc[n][4 * r2] * sc, acc[n][4 * r2 + 1] * sc,
               acc[n][4 * r2 + 2] * sc, acc[n][4 * r2 + 3] * sc};
      *(v4f*)(op + 8 * r2) = o;
    }
  }
}

extern "C" void kernel_launch(void* const* d_in, const int* in_sizes, int n_in,
                              void* d_out, int out_size, void* d_ws, size_t ws_size,
                              hipStream_t stream) {
  const float* noise = (const float*)d_in[0];   // (2, 8, 9095) fp32
  const float* filt  = (const float*)d_in[1];   // (128, 5000) fp32
  const float* scale = (const float*)d_in[2];   // (1, 128, 1) fp32
  float* out = (float*)d_out;                   // (2, 1024, 4096) fp32

  unsigned short* swz = (unsigned short*)d_ws;              // 1.34 MB
  float* xpad = (float*)((char*)d_ws + SWZ_BYTES);          // 16 x 9344 fp32 + tail

  const int pad_blocks = (NBC * XPS + XTAIL + 255) / 256;   // 585
  build_pre<<<313 + pad_blocks, 256, 0, stream>>>(filt, noise, swz, xpad);
  blur_mfma<<<2048, 64, 0, stream>>>(xpad, swz, scale, out);
}

// Round 5
// 122.119 us; speedup vs baseline: 10.0773x; 10.0773x over previous
//
#include <hip/hip_runtime.h>
#include <hip/hip_bf16.h>

// BlurredNoise via MFMA implicit GEMM, round 13 = round 12 minus scratch bug.
// R12 root cause (rule #20): ap = ((U&1?g:0)+i)&1 with RUNTIME g (NG>1,
// #pragma unroll 1) made areg[] runtime-indexed -> compiler demoted it to
// scratch -> serial store/load round-trip in every k-step (VALUBusy 45%,
// MfmaUtil 1%, 20x). Same bug explains R11 (+66MB scratch writes).
// Fix: every segment is single-group (NG=1): multi-group spans split into
// separate run_seg calls (W2 -> 3x U=25, W1 -> 7x U=27). g folds to 0,
// ap = i&1 is compile-time under full unroll; no group machinery at all.
// Each call stages its own 512-entry x window (8 shifted bf16 copies) then
// runs U straight-line steps: 1 ds_read_b128 A-fragment feeds all W live
// 32x32x16 MFMAs; B register-rotated from global with depth-D prefetch.
// out[bc][F][t] = scale[F] * sum_j x[bc][t+j] * k[F][j]

#define KS      5000
#define IN_SEQ  9095
#define T_OUT   4096
#define NBC     16
#define NF      128
#define NSTEP   313               // 16-tap k-steps
#define SWZSTEP 328               // padded per-tile step stride (rows)
#define CSTRIDE 1056              // bytes; /4 = 264 == 8 mod 32 -> uniform banks
#define XBUF    (8*CSTRIDE)       // 8448 B: 8 shifted copies, single buffer
#define XPS     9344              // padded x row stride (floats), front pad 32
#define XTAIL   256               // zero tail for staging over-reads (unread)
#define SWZ_BYTES (4*SWZSTEP*1024)    // 1,343,488

typedef __attribute__((ext_vector_type(8)))  short v8s;
typedef __attribute__((ext_vector_type(4)))  float v4f;
typedef __attribute__((ext_vector_type(16))) float v16f;

__device__ __forceinline__ unsigned short f2b(float v) {
  union { __hip_bfloat16 h; unsigned short u; } cv;
  cv.h = __float2bfloat16(v);   // RNE
  return cv.u;
}

// ---- fused pre-kernel: (a) filters -> 32x32x16 B-frags; (b) padded x copy ----
__global__ void build_pre(const float* __restrict__ filt,
                          const float* __restrict__ noise,
                          unsigned short* __restrict__ swz,
                          float* __restrict__ xpad) {
  const int b = blockIdx.x;
  if (b < 313) {                       // swz job: 4 tiles x 313 steps, 64 lanes/frag
    const int i = b * 256 + threadIdx.x;
    if (i >= 4 * NSTEP * 64) return;
    const int lane = i & 63;
    const int frag = i >> 6;
    const int ft = frag / NSTEP;
    const int s  = frag - ft * NSTEP;
    const int col = lane & 31;          // filter within tile
    const int hi  = lane >> 5;          // k-group (8 taps)
    const int jg0 = KS - 16 * (s + 1) + 8 * hi;
    const float* row = filt + (size_t)(ft * 32 + col) * KS;
    unsigned short o[8];
    #pragma unroll
    for (int j = 0; j < 8; ++j) {
      int jg = jg0 + j;
      int jc = jg < 0 ? 0 : jg;          // clamp ADDRESS, select VALUE
      float v = (jg >= 0) ? row[jc] : 0.0f;
      o[j] = f2b(v);
    }
    *(uint4*)(swz + (((size_t)(ft * SWZSTEP + s)) << 9) + (lane << 3)) = *(uint4*)o;
  } else {                             // xpad job: 16 x XPS (+tail), zeros outside
    const int i = (b - 313) * 256 + threadIdx.x;
    if (i >= NBC * XPS + XTAIL) return;
    const int r = i / XPS;
    const int pcol = i - r * XPS;
    const int lg = pcol - 32;
    xpad[i] = (r < NBC && lg >= 0 && lg < IN_SEQ) ? noise[r * IN_SEQ + lg] : 0.0f;
  }
}

// ---- one single-group constant-width segment of the k-loop ----
// W: live 32-F tiles (tiles 4-W..3); U: steps (<=30, staging window cap);
// SB: first step; D: B-prefetch depth (any D<=U; refill over-reads land in
// later steps or allocated pad rows, values unused). Fully straight-line:
// stage x window once, then U steps of {A ds_read_b128 prefetch, W MFMA,
// W B-refill global b128}. xb: LDS base (NO restrict - staging stores and
// A-reads load through the same provenance, ds order preserved).
template<int W, int U, int SB, int D>
__device__ __forceinline__ void run_seg(
    const char* __restrict__ swzg, const float* __restrict__ xn,
    char* xb, int xrd_off, int t0, int lane, v16f (&acc)[4])
{
  v8s breg[D][W];
  v8s areg[2];
  const char* xrd = xb + xrd_off;      // may-alias xb: ds ordering preserved

  const char* sp[W];
  #pragma unroll
  for (int w = 0; w < W; ++w)
    sp[w] = swzg + (((size_t)((4 - W + w) * SWZSTEP + SB)) << 10) + 16 * lane;

  // stage this segment's x window: 8 shifted bf16 copies of 512 entries
  {
    const int wb = t0 + KS - 16 * (SB + U);
    float4 xr[4];
    #pragma unroll
    for (int ii = 0; ii < 4; ++ii)
      xr[ii] = *(const float4*)(xn + (wb + 8 * lane + 4 * ii));
    const float* f = (const float*)xr;
    unsigned u8v[8];
    #pragma unroll
    for (int j = 0; j < 8; ++j)
      u8v[j] = (unsigned)f2b(f[2 * j]) | ((unsigned)f2b(f[2 * j + 1]) << 16);
    auto AL = [](unsigned hi, unsigned lo) { return (lo >> 16) | (hi << 16); };
    char* buf = xb + 16 * lane;
    #pragma unroll
    for (int c = 0; c < 8; ++c) {
      const int h = c >> 1;
      uint4 wv;
      if ((c & 1) == 0)
        wv = (uint4){u8v[h], u8v[h + 1], u8v[h + 2], u8v[h + 3]};
      else
        wv = (uint4){AL(u8v[h + 1], u8v[h]),     AL(u8v[h + 2], u8v[h + 1]),
                     AL(u8v[h + 3], u8v[h + 2]), AL(u8v[h + 4], u8v[h + 3])};
      *(uint4*)(buf + c * CSTRIDE) = wv;
    }
  }

  // B prologue depth D; A step 0 (entry offset 32*(U-1): steps walk down)
  #pragma unroll
  for (int d = 0; d < D; ++d)
    #pragma unroll
    for (int w = 0; w < W; ++w)
      breg[d][w] = *(const v8s*)(sp[w] + (d << 10));
  areg[0] = *(const v8s*)(xrd + 32 * (U - 1));

  #pragma unroll
  for (int i = 0; i < U; ++i) {
    const int ap = i & 1;               // compile-time under full unroll
    // A prefetch for next step (dead re-read at i==U-1)
    const int un = (i + 1 < U) ? (U - 2 - i) : (U - 1);
    areg[ap ^ 1] = *(const v8s*)(xrd + 32 * un);
    // MFMA: one A fragment x W live B tiles
    #pragma unroll
    for (int w = 0; w < W; ++w)
      acc[4 - W + w] = __builtin_amdgcn_mfma_f32_32x32x16_bf16(
          areg[ap], breg[i % D][w], acc[4 - W + w], 0, 0, 0);
    // B refill: slot i%D <- step i+D (over-reads unused / pad rows)
    #pragma unroll
    for (int w = 0; w < W; ++w)
      breg[i % D][w] = *(const v8s*)(sp[w] + ((i + D) << 10));
  }
}

// ---- main kernel: 2048 blocks x 64 threads, identical waves, barrier-free ----
__global__ __launch_bounds__(64, 2) void blur_mfma(
    const float* __restrict__ xpad,
    const unsigned short* __restrict__ swz,
    const float* __restrict__ scale,
    float* __restrict__ out)
{
  __shared__ __align__(16) char xb[XBUF];   // 8448 B
  const int lane = threadIdx.x;
  const int b  = blockIdx.x;
  const int bc = b >> 7;                 // 16 bc x 128 t-chunks
  const int t0 = (b & 127) << 5;         // 32 output t per wave
  const int row = lane & 31, hi = lane >> 5;
  const float* __restrict__ xn = xpad + (size_t)bc * XPS + 32;  // logical origin
  const char* swzg = (const char*)swz;
  // A-read: copy c=row&7, byte 16*(row>>3) + 16*hi (+32*u' per step)
  const int xrd_off = (row & 7) * CSTRIDE + 16 * (row >> 3) + 16 * hi;

  v16f acc[4];
  #pragma unroll
  for (int n = 0; n < 4; ++n)
    #pragma unroll
    for (int j = 0; j < 16; ++j) acc[n][j] = 0.0f;

  // segments <W, U, SB, D>, all single-group; live: W4 s<20, W3 <49,
  // W2 <124, W1 <313. 20+29+3*25+7*27 = 313.
  run_seg<4, 20,   0,  3>(swzg, xn, xb, xrd_off, t0, lane, acc);
  run_seg<3, 29,  20,  4>(swzg, xn, xb, xrd_off, t0, lane, acc);
  run_seg<2, 25,  49,  6>(swzg, xn, xb, xrd_off, t0, lane, acc);
  run_seg<2, 25,  74,  6>(swzg, xn, xb, xrd_off, t0, lane, acc);
  run_seg<2, 25,  99,  6>(swzg, xn, xb, xrd_off, t0, lane, acc);
  run_seg<1, 27, 124, 12>(swzg, xn, xb, xrd_off, t0, lane, acc);
  run_seg<1, 27, 151, 12>(swzg, xn, xb, xrd_off, t0, lane, acc);
  run_seg<1, 27, 178, 12>(swzg, xn, xb, xrd_off, t0, lane, acc);
  run_seg<1, 27, 205, 12>(swzg, xn, xb, xrd_off, t0, lane, acc);
  run_seg<1, 27, 232, 12>(swzg, xn, xb, xrd_off, t0, lane, acc);
  run_seg<1, 27, 259, 12>(swzg, xn, xb, xrd_off, t0, lane, acc);
  run_seg<1, 27, 286, 12>(swzg, xn, xb, xrd_off, t0, lane, acc);

  // epilogue: D col=lane&31 -> F, row=(reg&3)+8*(reg>>2)+4*hi -> t offset
  #pragma unroll
  for (int n = 0; n < 4; ++n) {
    const int F = 32 * n + row;
    const float sc = scale[F];
    float* op = out + (size_t)(bc * NF + F) * T_OUT + t0 + 4 * hi;
    #pragma unroll
    for (int r2 = 0; r2 < 4; ++r2) {
      v4f o = {acc[n][4 * r2] * sc, acc[n][4 * r2 + 1] * sc,
               acc[n][4 * r2 + 2] * sc, acc[n][4 * r2 + 3] * sc};
      *(v4f*)(op + 8 * r2) = o;
    }
  }
}

extern "C" void kernel_launch(void* const* d_in, const int* in_sizes, int n_in,
                              void* d_out, int out_size, void* d_ws, size_t ws_size,
                              hipStream_t stream) {
  const float* noise = (const float*)d_in[0];   // (2, 8, 9095) fp32
  const float* filt  = (const float*)d_in[1];   // (128, 5000) fp32
  const float* scale = (const float*)d_in[2];   // (1, 128, 1) fp32
  float* out = (float*)d_out;                   // (2, 1024, 4096) fp32

  unsigned short* swz = (unsigned short*)d_ws;              // 1.34 MB
  float* xpad = (float*)((char*)d_ws + SWZ_BYTES);          // 16 x 9344 fp32 + tail

  const int pad_blocks = (NBC * XPS + XTAIL + 255) / 256;   // 585
  build_pre<<<313 + pad_blocks, 256, 0, stream>>>(filt, noise, swz, xpad);
  blur_mfma<<<2048, 64, 0, stream>>>(xpad, swz, scale, out);
}